// Round 20
// baseline (43.873 us; speedup 1.0000x reference)
//
#include <hip/hip_runtime.h>
#include <hip/hip_bf16.h>

#define HIDDEN 64
#define BATCH 2048
#define SFULL 1024
#define SM1 1023
#define LN_CLAMP -23.025850929940457f  // ln(1e-10)
#define SP_PER 16                      // grid.y = 64 -> 64*16 = 1024 sp slots

typedef __bf16 bf16x8 __attribute__((ext_vector_type(8)));
typedef float  f32x4  __attribute__((ext_vector_type(4)));
typedef short  s16x2  __attribute__((ext_vector_type(2)));

// Fragment cache (16x16x32 shape, R5-verified layout): 19 units [64][16B].
//  u 0..3  : a1[mt]      (b1 folded at k=3)
//  u 4..11 : a2[mt][c]   (u = 4 + mt*2 + c)
//  u 12,13 : a3[c]
//  u 14..17: c2init[mt]  (f32x4)
//  u 18    : c3init      (f32x4, bout on g==0)
#define FRAG_UNITS 19

// Row permutation mapping MFMA D-layout rows to B-layout k-indices (16x16).
// Hardware-verified R2-R5/R14 (absmax 0.0).
__device__ __forceinline__ int permrow(int rho) {
    return 32 * ((rho >> 4) >> 1) + 8 * ((rho >> 2) & 3) + 4 * ((rho >> 4) & 1) + (rho & 3);
}

// truncating bf16 pack of 2 f32 (RTZ) -- verified R9+
__device__ __forceinline__ unsigned pkt(float lo, float hi) {
    return __builtin_amdgcn_perm(__float_as_uint(hi), __float_as_uint(lo), 0x07060302u);
}
// packed relu on 2 bf16 (int16 max-with-0) -- verified R11+
__device__ __forceinline__ unsigned rp(unsigned x) {
    s16x2 v = __builtin_bit_cast(s16x2, x);
    s16x2 z = {0, 0};
    v = __builtin_elementwise_max(v, z);
    return __builtin_bit_cast(unsigned, v);
}

// relu+pack: B-frag c from accs a=acc[2c], b=acc[2c+1]
// (R5/R14-verified mapping hf[c][j] = acc[2c + (j>>2)][j&3])
__device__ __forceinline__ bf16x8 relu_pack2(const f32x4 a, const f32x4 b) {
    union { unsigned u[4]; bf16x8 v; } r;
    r.u[0] = rp(pkt(a[0], a[1]));
    r.u[1] = rp(pkt(a[2], a[3]));
    r.u[2] = rp(pkt(b[0], b[1]));
    r.u[3] = rp(pkt(b[2], b[3]));
    return r.v;
}

// feature B-frag {xt, t, x0, 1, ...}; only g==0 k=0..3 reach nonzero A rows
__device__ __forceinline__ bf16x8 featpk(float xt, float t, float x0) {
    union { unsigned u[4]; bf16x8 v; } r;
    r.u[0] = pkt(xt, t);
    r.u[1] = pkt(x0, 1.0f);
    r.u[2] = r.u[0]; r.u[3] = r.u[1];
    return r.v;
}

// ---------------- Kernel 0: fragment gather, 19 blocks (1 unit each) -------
// Same math as R5's verified setup; block-parallel latency chains.
__global__ __launch_bounds__(64) void frag_setup_kernel(
    const float* __restrict__ W1, const float* __restrict__ b1,
    const float* __restrict__ W2, const float* __restrict__ b2,
    const float* __restrict__ Wout, const float* __restrict__ bout,
    char* __restrict__ F)
{
    const int l   = threadIdx.x;     // 0..63
    const int u   = blockIdx.x;      // unit 0..18
    const int col = l & 15;
    const int g   = l >> 4;

    if (u < 4) {
        // a1[mt]: A[16mt+col][8g+j] = W1aug[k][permrow(16mt+col)]
        const int p2 = permrow(16 * u + col);
        bf16x8 v;
#pragma unroll
        for (int j = 0; j < 8; ++j) {
            const int k = 8 * g + j;
            v[j] = (k < 3) ? (__bf16)W1[k * 64 + p2]
                 : (k == 3) ? (__bf16)b1[p2] : (__bf16)0.0f;
        }
        *(bf16x8*)(F + ((u * 64 + l) << 4)) = v;
    } else if (u < 12) {
        // a2[mt][c]: A[16mt+col][32c+8g+j] = W2[k][permrow(16mt+col)]
        const int mt = (u - 4) >> 1;
        const int c  = (u - 4) & 1;
        const int p2 = permrow(16 * mt + col);
        bf16x8 v;
#pragma unroll
        for (int j = 0; j < 8; ++j)
            v[j] = (__bf16)W2[(32 * c + 8 * g + j) * 64 + p2];
        *(bf16x8*)(F + ((u * 64 + l) << 4)) = v;
    } else if (u < 14) {
        // a3[c]: A[col][32c+8g+j] = (col<3)? Wout[k][col] : 0
        const int c = u - 12;
        bf16x8 v;
#pragma unroll
        for (int j = 0; j < 8; ++j)
            v[j] = (col < 3) ? (__bf16)Wout[(32 * c + 8 * g + j) * 3 + col] : (__bf16)0.0f;
        *(bf16x8*)(F + ((u * 64 + l) << 4)) = v;
    } else if (u < 18) {
        // c2init[mt]: reg r = b2[permrow(16mt + 4g + r)]
        const int mt = u - 14;
        f32x4 v;
#pragma unroll
        for (int r = 0; r < 4; ++r)
            v[r] = b2[permrow(16 * mt + 4 * g + r)];
        *(f32x4*)(F + ((u * 64 + l) << 4)) = v;
    } else {
        // c3init: bout on g==0 rows 0..2
        f32x4 v = {0.f, 0.f, 0.f, 0.f};
        if (g == 0) { v[0] = bout[0]; v[1] = bout[1]; v[2] = bout[2]; }
        *(f32x4*)(F + ((u * 64 + l) << 4)) = v;
    }
}

// ---------------- Kernel 1: 3-layer MLP, 16x16x32, register frags ----------
// grid (32, 64), block 256 (4 waves), __launch_bounds__(256,3).
// Wave owns 16 points b = (blockIdx.x*4+wv)*16 + (lane&15); 16 sp iterations.
// All weight frags in REGISTERS (~76 VGPR) + small f32x4 accs (~36 AGPR
// peak) -> total ~137 regs, the only config allowing 3+ waves/SIMD with a
// zero-LDS chain. Per sp (14 MFMA): L1 4 -> pack -> L2 4+4 -> pack -> L3 2.
__global__ __launch_bounds__(256, 3) void mlp_z_kernel(
    const float* __restrict__ ys,    // (B, S, 2)
    const char* __restrict__ F,      // fragment cache
    float* __restrict__ z)           // (SM1, BATCH)
{
    const int l   = threadIdx.x & 63;
    const int wv  = threadIdx.x >> 6;
    const int col = l & 15;

    const int b   = (blockIdx.x * 4 + wv) * 16 + col;
    const int sp0 = blockIdx.y * SP_PER;
    const int omax = (SFULL - 1) - sp0;

    // ---- coalesced fragment loads (L2-hot) ----
    bf16x8 a1[4], a2[4][2], a3[2];
    f32x4 c2init[4], c3init;
#pragma unroll
    for (int mt = 0; mt < 4; ++mt) {
        a1[mt]     = *(const bf16x8*)(F + ((mt * 64 + l) << 4));
        a2[mt][0]  = *(const bf16x8*)(F + (((4 + mt * 2) * 64 + l) << 4));
        a2[mt][1]  = *(const bf16x8*)(F + (((5 + mt * 2) * 64 + l) << 4));
        c2init[mt] = *(const f32x4*)(F + (((14 + mt) * 64 + l) << 4));
    }
    a3[0]  = *(const bf16x8*)(F + ((12 * 64 + l) << 4));
    a3[1]  = *(const bf16x8*)(F + ((13 * 64 + l) << 4));
    c3init = *(const f32x4*)(F + ((18 * 64 + l) << 4));

    const f32x4 zero4 = {0.f, 0.f, 0.f, 0.f};

    const float2* base2 = reinterpret_cast<const float2*>(ys) + ((size_t)b * SFULL + sp0);
    float* zb = z + (size_t)sp0 * BATCH + b;

    float2 q0 = base2[0];
    float2 q1 = base2[min(1, omax)];
    float2 qn = base2[min(2, omax)];

    for (int it = 0; it < SP_PER; ++it) {
        const float2 qn2 = base2[min(it + 3, omax)];  // prefetch

        const float x0 = q0.y, t = q1.x, xt = q1.y;
        const bf16x8 f0 = featpk(xt, t, x0);

        // ---- layer 1 (b1 folded) ----
        f32x4 acc1[4];
        acc1[0] = __builtin_amdgcn_mfma_f32_16x16x32_bf16(a1[0], f0, zero4, 0, 0, 0);
        acc1[1] = __builtin_amdgcn_mfma_f32_16x16x32_bf16(a1[1], f0, zero4, 0, 0, 0);
        acc1[2] = __builtin_amdgcn_mfma_f32_16x16x32_bf16(a1[2], f0, zero4, 0, 0, 0);
        acc1[3] = __builtin_amdgcn_mfma_f32_16x16x32_bf16(a1[3], f0, zero4, 0, 0, 0);

        bf16x8 hf[2];
        hf[0] = relu_pack2(acc1[0], acc1[1]);
        hf[1] = relu_pack2(acc1[2], acc1[3]);

        // ---- layer 2 (C = c2init; 4 parallel chains of 2) ----
        f32x4 acc2[4];
        acc2[0] = __builtin_amdgcn_mfma_f32_16x16x32_bf16(a2[0][0], hf[0], c2init[0], 0, 0, 0);
        acc2[1] = __builtin_amdgcn_mfma_f32_16x16x32_bf16(a2[1][0], hf[0], c2init[1], 0, 0, 0);
        acc2[2] = __builtin_amdgcn_mfma_f32_16x16x32_bf16(a2[2][0], hf[0], c2init[2], 0, 0, 0);
        acc2[3] = __builtin_amdgcn_mfma_f32_16x16x32_bf16(a2[3][0], hf[0], c2init[3], 0, 0, 0);
        acc2[0] = __builtin_amdgcn_mfma_f32_16x16x32_bf16(a2[0][1], hf[1], acc2[0], 0, 0, 0);
        acc2[1] = __builtin_amdgcn_mfma_f32_16x16x32_bf16(a2[1][1], hf[1], acc2[1], 0, 0, 0);
        acc2[2] = __builtin_amdgcn_mfma_f32_16x16x32_bf16(a2[2][1], hf[1], acc2[2], 0, 0, 0);
        acc2[3] = __builtin_amdgcn_mfma_f32_16x16x32_bf16(a2[3][1], hf[1], acc2[3], 0, 0, 0);

        bf16x8 h2f[2];
        h2f[0] = relu_pack2(acc2[0], acc2[1]);
        h2f[1] = relu_pack2(acc2[2], acc2[3]);

        // ---- layer 3 (bout folded into c3init) ----
        f32x4 acc3;
        acc3 = __builtin_amdgcn_mfma_f32_16x16x32_bf16(a3[0], h2f[0], c3init, 0, 0, 0);
        acc3 = __builtin_amdgcn_mfma_f32_16x16x32_bf16(a3[1], h2f[1], acc3, 0, 0, 0);

        // Hermite (g==0 lanes hold c0,c1,c2 = acc3[0..2])
        const float zv = fmaf(acc3[2], fmaf(4.0f * xt, xt, -2.0f),
                         fmaf(acc3[1], xt + xt, acc3[0]));

        if (l < 16 && sp0 + it < SM1)
            zb[(size_t)it * BATCH] = zv;

        q0 = q1; q1 = qn; qn = qn2;
    }
}

// ---------------- reduction helpers ----------------
__device__ __forceinline__ float blk_reduce_max(float v) {
    __shared__ float s[4];
#pragma unroll
    for (int off = 32; off >= 1; off >>= 1) v = fmaxf(v, __shfl_xor(v, off));
    if ((threadIdx.x & 63) == 0) s[threadIdx.x >> 6] = v;
    __syncthreads();
    v = fmaxf(fmaxf(s[0], s[1]), fmaxf(s[2], s[3]));
    __syncthreads();
    return v;
}

__device__ __forceinline__ float blk_reduce_sum(float v) {
    __shared__ float s[4];
#pragma unroll
    for (int off = 32; off >= 1; off >>= 1) v += __shfl_xor(v, off);
    if ((threadIdx.x & 63) == 0) s[threadIdx.x >> 6] = v;
    __syncthreads();
    v = (s[0] + s[1]) + (s[2] + s[3]);
    __syncthreads();
    return v;
}

// ---------------- Kernel 2: per-column softmax + logclip sum ----------------
__global__ __launch_bounds__(256) void col_softmax_kernel(
    const float* __restrict__ z, float* __restrict__ colsum)
{
    const int sp = blockIdx.x;
    const int tid = threadIdx.x;
    const float* col = z + (size_t)sp * BATCH;

    float vals[8];
    float m = -3.4e38f;
#pragma unroll
    for (int i = 0; i < 8; ++i) {
        vals[i] = col[tid + 256 * i];
        m = fmaxf(m, vals[i]);
    }
    const float M = blk_reduce_max(m);

    float se = 0.0f;
#pragma unroll
    for (int i = 0; i < 8; ++i) se += __expf(vals[i] - M);
    const float S = blk_reduce_sum(se);
    const float L = __logf(S);

    float acc = 0.0f;
#pragma unroll
    for (int i = 0; i < 8; ++i) acc += fmaxf(vals[i] - M - L, LN_CLAMP);
    const float T = blk_reduce_sum(acc);
    if (tid == 0) colsum[sp] = T;
}

// ---------------- Kernel 3: final scalar ----------------
__global__ __launch_bounds__(256) void final_reduce_kernel(
    const float* __restrict__ colsum, float* __restrict__ out)
{
    const int tid = threadIdx.x;
    float v = 0.0f;
    for (int i = tid; i < SM1; i += 256) v += colsum[i];
    const float T = blk_reduce_sum(v);
    if (tid == 0) out[0] = T / (float)BATCH;
}

extern "C" void kernel_launch(void* const* d_in, const int* in_sizes, int n_in,
                              void* d_out, int out_size, void* d_ws, size_t ws_size,
                              hipStream_t stream) {
    const float* ys   = (const float*)d_in[0];
    const float* W1   = (const float*)d_in[1];
    const float* b1   = (const float*)d_in[2];
    const float* W2   = (const float*)d_in[3];
    const float* b2   = (const float*)d_in[4];
    const float* Wout = (const float*)d_in[5];
    const float* bout = (const float*)d_in[6];
    float* out = (float*)d_out;

    float* z      = (float*)d_ws;                         // SM1*BATCH floats
    float* colsum = z + (size_t)SM1 * BATCH;              // SM1 floats
    size_t fo = ((size_t)SM1 * BATCH + SM1) * sizeof(float);
    fo = (fo + 15) & ~(size_t)15;
    char* F = (char*)d_ws + fo;                           // 19*64*16 = 19 KB

    frag_setup_kernel<<<FRAG_UNITS, 64, 0, stream>>>(W1, b1, W2, b2, Wout, bout, F);
    dim3 grid1(32, 64);  // 32*4 waves * 16 pts = 2048 b ; 64*16 = 1024 sp slots
    mlp_z_kernel<<<grid1, 256, 0, stream>>>(ys, F, z);
    col_softmax_kernel<<<SM1, 256, 0, stream>>>(z, colsum);
    final_reduce_kernel<<<1, 256, 0, stream>>>(colsum, out);
}

// Round 21
// 42.399 us; speedup vs baseline: 1.0348x; 1.0348x over previous
//
#include <hip/hip_runtime.h>
#include <hip/hip_bf16.h>

#define HIDDEN 64
#define BATCH 2048
#define SFULL 1024
#define SM1 1023
#define LN_CLAMP -23.025850929940457f  // ln(1e-10)
#define SP_PER 16                      // grid.y = 64 -> 64*16 = 1024 sp slots

typedef __bf16 bf16x8 __attribute__((ext_vector_type(8)));
typedef float  f32x4  __attribute__((ext_vector_type(4)));
typedef float  f32x16 __attribute__((ext_vector_type(16)));
typedef short  s16x2  __attribute__((ext_vector_type(2)));

// Fragment cache: 16 units of [64 lanes][16B] (R11-verified layout).
//  u 0,1   : a1[mt]     (b1 folded at k=3)
//  u 2..9  : a2[mt][c]  (u = 2 + mt*4 + c)
//  u 10..13: a3[c]
//  u 14,15 : a2b[mt]    bias frag (b2 at k_local=0)
#define FRAG_UNITS 16

// sigma mapping (hardware-verified R7-R19, absmax 0.0)
__device__ __forceinline__ int sig(int rg) {
    return 16 * ((rg >> 3) & 3) + 8 * ((rg >> 2) & 1) + (rg & 3) + 4 * (rg >> 5);
}

// truncating bf16 pack (RTZ) -- verified R9+
__device__ __forceinline__ unsigned pkt(float lo, float hi) {
    return __builtin_amdgcn_perm(__float_as_uint(hi), __float_as_uint(lo), 0x07060302u);
}
// packed relu on 2 bf16 -- verified R11+
__device__ __forceinline__ unsigned rp(unsigned x) {
    s16x2 v = __builtin_bit_cast(s16x2, x);
    s16x2 z = {0, 0};
    v = __builtin_elementwise_max(v, z);
    return __builtin_bit_cast(unsigned, v);
}

// pack+relu two f32x16 D-frags into 4 B-frags (layout verified R7)
__device__ __forceinline__ void relu_pack4(const f32x16 lo, const f32x16 hi, bf16x8* out) {
#pragma unroll
    for (int c = 0; c < 4; ++c) {
        union { unsigned u[4]; bf16x8 v; } r;
        r.u[0] = rp(pkt(lo[4 * c + 0], lo[4 * c + 1]));
        r.u[1] = rp(pkt(lo[4 * c + 2], lo[4 * c + 3]));
        r.u[2] = rp(pkt(hi[4 * c + 0], hi[4 * c + 1]));
        r.u[3] = rp(pkt(hi[4 * c + 2], hi[4 * c + 3]));
        out[c] = r.v;
    }
}

// feature B-frag {xt, t, x0, 1, ...} (elems k>=4 multiply A=0)
__device__ __forceinline__ bf16x8 featpk(float xt, float t, float x0) {
    union { unsigned u[4]; bf16x8 v; } r;
    r.u[0] = pkt(xt, t);
    r.u[1] = pkt(x0, 1.0f);
    r.u[2] = r.u[0]; r.u[3] = r.u[1];
    return r.v;
}

// ---------------- Kernel 0: fragment gather, 16 blocks (1 unit each) -------
// Same math as R11's setup (hardware-verified); block-parallel so the
// scattered-load latency chains run concurrently.
__global__ __launch_bounds__(64) void frag_setup_kernel(
    const float* __restrict__ W1, const float* __restrict__ b1,
    const float* __restrict__ W2, const float* __restrict__ b2,
    const float* __restrict__ Wout, char* __restrict__ F)
{
    const int l    = threadIdx.x;    // 0..63
    const int u    = blockIdx.x;     // unit 0..15
    const int pcol = l & 31;
    const int hi   = l >> 5;

    bf16x8 v;
    if (u < 2) {
        const int hout = sig(32 * u + pcol);
#pragma unroll
        for (int j = 0; j < 8; ++j) {
            const int k = 8 * hi + j;
            v[j] = (k < 3) ? (__bf16)W1[k * 64 + hout]
                 : (k == 3) ? (__bf16)b1[hout] : (__bf16)0.0f;
        }
    } else if (u < 10) {
        const int mt = (u - 2) >> 2;
        const int c  = (u - 2) & 3;
        const int hout = sig(32 * mt + pcol);
#pragma unroll
        for (int j = 0; j < 8; ++j)
            v[j] = (__bf16)W2[(16 * c + 8 * hi + j) * 64 + hout];
    } else if (u < 14) {
        const int c = u - 10;
#pragma unroll
        for (int j = 0; j < 8; ++j) {
            const int k = 16 * c + 8 * hi + j;
            v[j] = (pcol < 3) ? (__bf16)Wout[k * 3 + pcol] : (__bf16)0.0f;
        }
    } else {
        const int mt = u - 14;
        const int hout = sig(32 * mt + pcol);
#pragma unroll
        for (int j = 0; j < 8; ++j)
            v[j] = (hi == 0 && j == 0) ? (__bf16)b2[hout] : (__bf16)0.0f;
    }
    *(bf16x8*)(F + ((u * 64 + l) << 4)) = v;
}

// ---------------- Kernel 1: 3-layer MLP, 32x32x16 MFMA (R11/R18-exact) -----
// grid (16, 64), block 256 (4 waves), __launch_bounds__(256,3).
// Wave owns 32 points b = (blockIdx.x*4+wv)*32 + (lane&31); 16 sp iterations.
// Per sp (16 MFMA): L1 2 -> pack -> L2 2 bias + 2x4 chain -> pack ->
// L3 serial 4 -> epilogue rows 0..2 (hi=0 lanes) -> store z[sp][b].
__global__ __launch_bounds__(256, 3) void mlp_z_kernel(
    const float* __restrict__ ys,    // (B, S, 2)
    const char* __restrict__ F,      // fragment cache
    const float* __restrict__ bout,  // (3)
    float* __restrict__ z)           // (SM1, BATCH)
{
    const int l    = threadIdx.x & 63;
    const int wv   = threadIdx.x >> 6;
    const int pcol = l & 31;
    const int hi   = l >> 5;

    const int b   = (blockIdx.x * 4 + wv) * 32 + pcol;
    const int sp0 = blockIdx.y * SP_PER;
    const int omax = (SFULL - 1) - sp0;

    // ---- coalesced fragment loads (L2-hot) ----
    bf16x8 a1[2], a2[2][4], a3[4], a2b[2];
#pragma unroll
    for (int mt = 0; mt < 2; ++mt) {
        a1[mt]  = *(const bf16x8*)(F + ((mt * 64 + l) << 4));
        a2b[mt] = *(const bf16x8*)(F + (((14 + mt) * 64 + l) << 4));
#pragma unroll
        for (int c = 0; c < 4; ++c)
            a2[mt][c] = *(const bf16x8*)(F + (((2 + mt * 4 + c) * 64 + l) << 4));
    }
#pragma unroll
    for (int c = 0; c < 4; ++c)
        a3[c] = *(const bf16x8*)(F + (((10 + c) * 64 + l) << 4));

    // B_one: B[k_local][*] = 1 at k_local==0 -> hi==0 lanes, halfword 0
    bf16x8 Bone;
    {
        union { unsigned u[4]; bf16x8 v; } r;
        r.u[0] = (hi == 0) ? 0x3F80u : 0u;  // bf16(1.0)
        r.u[1] = 0u; r.u[2] = 0u; r.u[3] = 0u;
        Bone = r.v;
    }

    const float bo0 = bout[0], bo1 = bout[1], bo2 = bout[2];

    f32x16 zero16;
#pragma unroll
    for (int i = 0; i < 16; ++i) zero16[i] = 0.0f;

    const float2* base2 = reinterpret_cast<const float2*>(ys) + ((size_t)b * SFULL + sp0);
    float* zb = z + (size_t)sp0 * BATCH + b;

    float2 q0 = base2[0];
    float2 q1 = base2[min(1, omax)];
    float2 qn = base2[min(2, omax)];

    for (int it = 0; it < SP_PER; ++it) {
        const float2 qn2 = base2[min(it + 3, omax)];  // prefetch

        const float x0 = q0.y, t = q1.x, xt = q1.y;
        const bf16x8 f0 = featpk(xt, t, x0);

        // ---- layer 1 (b1 folded) ----
        f32x16 acc1_0 = __builtin_amdgcn_mfma_f32_32x32x16_bf16(a1[0], f0, zero16, 0, 0, 0);
        f32x16 acc1_1 = __builtin_amdgcn_mfma_f32_32x32x16_bf16(a1[1], f0, zero16, 0, 0, 0);

        // L2 bias mfmas: independent of h1, hide under L1/pack
        f32x16 acc2_0 = __builtin_amdgcn_mfma_f32_32x32x16_bf16(a2b[0], Bone, zero16, 0, 0, 0);
        f32x16 acc2_1 = __builtin_amdgcn_mfma_f32_32x32x16_bf16(a2b[1], Bone, zero16, 0, 0, 0);

        bf16x8 h1f[4];
        relu_pack4(acc1_0, acc1_1, h1f);

        // ---- layer 2 ----
#pragma unroll
        for (int c = 0; c < 4; ++c) {
            acc2_0 = __builtin_amdgcn_mfma_f32_32x32x16_bf16(a2[0][c], h1f[c], acc2_0, 0, 0, 0);
            acc2_1 = __builtin_amdgcn_mfma_f32_32x32x16_bf16(a2[1][c], h1f[c], acc2_1, 0, 0, 0);
        }

        bf16x8 h2f[4];
        relu_pack4(acc2_0, acc2_1, h2f);

        // ---- layer 3 (serial 4; only rows 0..2 consumed) ----
        f32x16 acc3 = __builtin_amdgcn_mfma_f32_32x32x16_bf16(a3[0], h2f[0], zero16, 0, 0, 0);
#pragma unroll
        for (int c = 1; c < 4; ++c)
            acc3 = __builtin_amdgcn_mfma_f32_32x32x16_bf16(a3[c], h2f[c], acc3, 0, 0, 0);

        // epilogue (hi=0 lanes hold rows 0..2)
        const float c0 = acc3[0] + bo0;
        const float c1 = acc3[1] + bo1;
        const float c2 = acc3[2] + bo2;
        const float zv = fmaf(c2, fmaf(4.0f * xt, xt, -2.0f), fmaf(c1, xt + xt, c0));

        if (l < 32 && sp0 + it < SM1)
            zb[(size_t)it * BATCH] = zv;

        q0 = q1; q1 = qn; qn = qn2;
    }
}

// ---------------- reduction helpers ----------------
__device__ __forceinline__ float blk_reduce_max(float v) {
    __shared__ float s[4];
#pragma unroll
    for (int off = 32; off >= 1; off >>= 1) v = fmaxf(v, __shfl_xor(v, off));
    if ((threadIdx.x & 63) == 0) s[threadIdx.x >> 6] = v;
    __syncthreads();
    v = fmaxf(fmaxf(s[0], s[1]), fmaxf(s[2], s[3]));
    __syncthreads();
    return v;
}

__device__ __forceinline__ float blk_reduce_sum(float v) {
    __shared__ float s[4];
#pragma unroll
    for (int off = 32; off >= 1; off >>= 1) v += __shfl_xor(v, off);
    if ((threadIdx.x & 63) == 0) s[threadIdx.x >> 6] = v;
    __syncthreads();
    v = (s[0] + s[1]) + (s[2] + s[3]);
    __syncthreads();
    return v;
}

// ---------------- Kernel 2: per-column softmax + logclip sum ----------------
__global__ __launch_bounds__(256) void col_softmax_kernel(
    const float* __restrict__ z, float* __restrict__ colsum)
{
    const int sp = blockIdx.x;
    const int tid = threadIdx.x;
    const float* col = z + (size_t)sp * BATCH;

    float vals[8];
    float m = -3.4e38f;
#pragma unroll
    for (int i = 0; i < 8; ++i) {
        vals[i] = col[tid + 256 * i];
        m = fmaxf(m, vals[i]);
    }
    const float M = blk_reduce_max(m);

    float se = 0.0f;
#pragma unroll
    for (int i = 0; i < 8; ++i) se += __expf(vals[i] - M);
    const float S = blk_reduce_sum(se);
    const float L = __logf(S);

    float acc = 0.0f;
#pragma unroll
    for (int i = 0; i < 8; ++i) acc += fmaxf(vals[i] - M - L, LN_CLAMP);
    const float T = blk_reduce_sum(acc);
    if (tid == 0) colsum[sp] = T;
}

// ---------------- Kernel 3: final scalar ----------------
__global__ __launch_bounds__(256) void final_reduce_kernel(
    const float* __restrict__ colsum, float* __restrict__ out)
{
    const int tid = threadIdx.x;
    float v = 0.0f;
    for (int i = tid; i < SM1; i += 256) v += colsum[i];
    const float T = blk_reduce_sum(v);
    if (tid == 0) out[0] = T / (float)BATCH;
}

extern "C" void kernel_launch(void* const* d_in, const int* in_sizes, int n_in,
                              void* d_out, int out_size, void* d_ws, size_t ws_size,
                              hipStream_t stream) {
    const float* ys   = (const float*)d_in[0];
    const float* W1   = (const float*)d_in[1];
    const float* b1   = (const float*)d_in[2];
    const float* W2   = (const float*)d_in[3];
    const float* b2   = (const float*)d_in[4];
    const float* Wout = (const float*)d_in[5];
    const float* bout = (const float*)d_in[6];
    float* out = (float*)d_out;

    float* z      = (float*)d_ws;                         // SM1*BATCH floats
    float* colsum = z + (size_t)SM1 * BATCH;              // SM1 floats
    size_t fo = ((size_t)SM1 * BATCH + SM1) * sizeof(float);
    fo = (fo + 15) & ~(size_t)15;
    char* F = (char*)d_ws + fo;                           // 16*64*16 = 16 KB

    frag_setup_kernel<<<FRAG_UNITS, 64, 0, stream>>>(W1, b1, W2, b2, Wout, F);
    dim3 grid1(16, 64);  // 16*4 waves * 32 pts = 2048 b ; 64*16 = 1024 sp slots
    mlp_z_kernel<<<grid1, 256, 0, stream>>>(ys, F, bout, z);
    col_softmax_kernel<<<SM1, 256, 0, stream>>>(z, colsum);
    final_reduce_kernel<<<1, 256, 0, stream>>>(colsum, out);
}